// Round 5
// baseline (1786.415 us; speedup 1.0000x reference)
//
#include <hip/hip_runtime.h>
#include <stdint.h>

namespace {

constexpr int T_STEPS = 2048;
constexpr int BATCH   = 512;
constexpr int IN      = 64;
constexpr int H       = 128;
constexpr int OUT     = 10;
constexpr int BDIM    = 256;   // 4 waves
constexpr int CHUNK   = 16;    // x prefetch chunk (steps)
constexpr int NCHUNK  = T_STEPS / CHUNK;   // 128

typedef _Float16 half2v __attribute__((ext_vector_type(2)));

__device__ __forceinline__ float dot2(uint32_t a, uint32_t b, float c) {
#if __has_builtin(__builtin_amdgcn_fdot2)
    return __builtin_amdgcn_fdot2(__builtin_bit_cast(half2v, a),
                                  __builtin_bit_cast(half2v, b), c, false);
#else
    half2v av = __builtin_bit_cast(half2v, a);
    half2v bv = __builtin_bit_cast(half2v, b);
    return c + (float)av[0] * (float)bv[0] + (float)av[1] * (float)bv[1];
#endif
}

__device__ __forceinline__ uint32_t packh2(float lo, float hi) {
    half2v v; v[0] = (_Float16)lo; v[1] = (_Float16)hi;
    return __builtin_bit_cast(uint32_t, v);
}

__device__ __forceinline__ float fast_tanh(float x) {
    float e = __expf(2.0f * x);
    return 1.0f - 2.0f / (e + 1.0f);
}

// Sum over the 4-lane group {l, l^16, l^32, l^48}; result in ALL lanes.
// VALU permlane swaps instead of DS-latency shuffles. NOTE: must use inline
// asm with two distinct read-write operands — the builtin with identical
// operands can be register-coalesced, degenerating the swap (round-4 bug).
__device__ __forceinline__ float qsum(float v) {
    float x = v, y = v;
    asm("v_permlane16_swap_b32 %0, %1" : "+v"(x), "+v"(y));
    float s = x + y;                 // v[l] + v[l^16], every lane
    float p = s, q = s;
    asm("v_permlane32_swap_b32 %0, %1" : "+v"(p), "+v"(q));
    return p + q;                    // full 4-group sum, every lane
}

// Fused 2-layer scan, 1 batch row / block, pipelined L1(t) || L0(t+1).
// 4-way K-split: lane group q=(l>>4) owns K-quarter [q*32,q*32+32);
// each thread owns dims dlo = W*16+(l&15) and dhi = dlo+64.
__global__ __launch_bounds__(BDIM, 2) void rnn2_scan(
    const float* __restrict__ x,
    const float* __restrict__ hidden,
    const float* __restrict__ Wi0, const float* __restrict__ bi0,
    const float* __restrict__ Wh0, const float* __restrict__ bh0,
    const float* __restrict__ Wi1, const float* __restrict__ bi1,
    const float* __restrict__ Wh1, const float* __restrict__ bh1,
    const float* __restrict__ Wfc, const float* __restrict__ bfc,
    float* __restrict__ out)
{
    const int b   = blockIdx.x;
    const int tid = threadIdx.x;
    const int W   = tid >> 6;
    const int l   = tid & 63;
    const int q   = l >> 4;             // K-quarter 0..3
    const int dlo = W * 16 + (l & 15);
    const int dhi = dlo + 64;
    const bool hiq = (q & 1) != 0;      // odd quarter -> this lane finishes dhi
    const int  wd  = hiq ? dhi : dlo;   // dim this lane writes (l<32 writers)

    // h(t) parity: h?h[t & 1] holds h?(t); inits live in parity 1.
    __shared__ __align__(16) _Float16 h0h[2][H];
    __shared__ __align__(16) _Float16 h1h[2][H];
    __shared__ __align__(16) uint32_t xs[2][CHUNK][IN / 2];   // f16-packed x, 4 KB

    // ---- weights: f16 pairs, rows {dlo,dhi}, K-slice [q*32, q*32+32)
    uint32_t wh0a[16], wh0b[16], wi1a[16], wi1b[16], wh1a[16], wh1b[16];
    uint32_t wi0a[8], wi0b[8];
    {
        const float2* p;
        p = (const float2*)(Wh0 + dlo * H + q * 32);
        #pragma unroll
        for (int j = 0; j < 16; ++j) wh0a[j] = packh2(p[j].x, p[j].y);
        p = (const float2*)(Wh0 + dhi * H + q * 32);
        #pragma unroll
        for (int j = 0; j < 16; ++j) wh0b[j] = packh2(p[j].x, p[j].y);
        p = (const float2*)(Wi1 + dlo * H + q * 32);
        #pragma unroll
        for (int j = 0; j < 16; ++j) wi1a[j] = packh2(p[j].x, p[j].y);
        p = (const float2*)(Wi1 + dhi * H + q * 32);
        #pragma unroll
        for (int j = 0; j < 16; ++j) wi1b[j] = packh2(p[j].x, p[j].y);
        p = (const float2*)(Wh1 + dlo * H + q * 32);
        #pragma unroll
        for (int j = 0; j < 16; ++j) wh1a[j] = packh2(p[j].x, p[j].y);
        p = (const float2*)(Wh1 + dhi * H + q * 32);
        #pragma unroll
        for (int j = 0; j < 16; ++j) wh1b[j] = packh2(p[j].x, p[j].y);
        p = (const float2*)(Wi0 + dlo * IN + q * 16);
        #pragma unroll
        for (int j = 0; j < 8; ++j) wi0a[j] = packh2(p[j].x, p[j].y);
        p = (const float2*)(Wi0 + dhi * IN + q * 16);
        #pragma unroll
        for (int j = 0; j < 8; ++j) wi0b[j] = packh2(p[j].x, p[j].y);
    }
    const float bias0 = hiq ? (bi0[dhi] + bh0[dhi]) : (bi0[dlo] + bh0[dlo]);
    const float bias1 = hiq ? (bi1[dhi] + bh1[dhi]) : (bi1[dlo] + bh1[dlo]);

    // ---- init hidden into parity-1 buffers
    if (tid < H) h0h[1][tid]     = (_Float16)hidden[b * H + tid];
    else         h1h[1][tid - H] = (_Float16)hidden[BATCH * H + b * H + (tid - H)];

    // ---- x prefetch: chunk0 packed into LDS, chunk1 raw in regs
    const float4* xrow = (const float4*)(x + (size_t)b * T_STEPS * IN);
    float4 R;
    {
        float4 v = xrow[tid];
        uint2 pk; pk.x = packh2(v.x, v.y); pk.y = packh2(v.z, v.w);
        ((uint2*)&xs[0][0][0])[tid] = pk;
        R = xrow[256 + tid];
    }
    __syncthreads();

    // ================= peel: L0(0) -> h0(0) into h0h[0]
    {
        const uint4* hp = (const uint4*)&h0h[1][q * 32];
        const uint4* xq = (const uint4*)&xs[0][0][q * 8];
        float A0=0,A1=0,A2=0,A3=0, B0=0,B1=0,B2=0,B3=0;
        #pragma unroll
        for (int r = 0; r < 4; ++r) {
            uint4 hv = hp[r];
            A0=dot2(wh0a[4*r+0],hv.x,A0); A1=dot2(wh0a[4*r+1],hv.y,A1);
            A2=dot2(wh0a[4*r+2],hv.z,A2); A3=dot2(wh0a[4*r+3],hv.w,A3);
            B0=dot2(wh0b[4*r+0],hv.x,B0); B1=dot2(wh0b[4*r+1],hv.y,B1);
            B2=dot2(wh0b[4*r+2],hv.z,B2); B3=dot2(wh0b[4*r+3],hv.w,B3);
        }
        #pragma unroll
        for (int r = 0; r < 2; ++r) {
            uint4 xv = xq[r];
            A0=dot2(wi0a[4*r+0],xv.x,A0); A1=dot2(wi0a[4*r+1],xv.y,A1);
            A2=dot2(wi0a[4*r+2],xv.z,A2); A3=dot2(wi0a[4*r+3],xv.w,A3);
            B0=dot2(wi0b[4*r+0],xv.x,B0); B1=dot2(wi0b[4*r+1],xv.y,B1);
            B2=dot2(wi0b[4*r+2],xv.z,B2); B3=dot2(wi0b[4*r+3],xv.w,B3);
        }
        float sA = qsum((A0+A1)+(A2+A3));
        float sB = qsum((B0+B1)+(B2+B3));
        float v0 = fast_tanh((hiq ? sB : sA) + bias0);
        if (l < 32) h0h[0][wd] = (_Float16)v0;
    }
    __syncthreads();

    // ================= main loop: interval t computes L1(t) || L0(t+1)
    for (int t = 0; t < T_STEPS - 1; ++t) {
        const int s  = t + 1;            // x step consumed by L0
        const int c  = s >> 4;
        const int ph = s & (CHUNK - 1);
        const int rp = t & 1;

        const uint4* hp = (const uint4*)&h0h[rp][q * 32];       // h0(t): feeds Wh0 AND Wi1
        const uint4* gp = (const uint4*)&h1h[rp ^ 1][q * 32];   // h1(t-1)
        const uint4* xq = (const uint4*)&xs[c & 1][ph][q * 8];

        float A0=0,A1=0,A2=0,A3=0;   // L0(t+1), dlo
        float B0=0,B1=0,B2=0,B3=0;   // L0(t+1), dhi
        float C0=0,C1=0,C2=0,C3=0;   // L1(t),   dlo
        float D0=0,D1=0,D2=0,D3=0;   // L1(t),   dhi
        #pragma unroll
        for (int r = 0; r < 4; ++r) {
            uint4 hv = hp[r];
            A0=dot2(wh0a[4*r+0],hv.x,A0); A1=dot2(wh0a[4*r+1],hv.y,A1);
            A2=dot2(wh0a[4*r+2],hv.z,A2); A3=dot2(wh0a[4*r+3],hv.w,A3);
            B0=dot2(wh0b[4*r+0],hv.x,B0); B1=dot2(wh0b[4*r+1],hv.y,B1);
            B2=dot2(wh0b[4*r+2],hv.z,B2); B3=dot2(wh0b[4*r+3],hv.w,B3);
            C0=dot2(wi1a[4*r+0],hv.x,C0); C1=dot2(wi1a[4*r+1],hv.y,C1);
            C2=dot2(wi1a[4*r+2],hv.z,C2); C3=dot2(wi1a[4*r+3],hv.w,C3);
            D0=dot2(wi1b[4*r+0],hv.x,D0); D1=dot2(wi1b[4*r+1],hv.y,D1);
            D2=dot2(wi1b[4*r+2],hv.z,D2); D3=dot2(wi1b[4*r+3],hv.w,D3);
            uint4 gv = gp[r];
            C0=dot2(wh1a[4*r+0],gv.x,C0); C1=dot2(wh1a[4*r+1],gv.y,C1);
            C2=dot2(wh1a[4*r+2],gv.z,C2); C3=dot2(wh1a[4*r+3],gv.w,C3);
            D0=dot2(wh1b[4*r+0],gv.x,D0); D1=dot2(wh1b[4*r+1],gv.y,D1);
            D2=dot2(wh1b[4*r+2],gv.z,D2); D3=dot2(wh1b[4*r+3],gv.w,D3);
        }
        #pragma unroll
        for (int r = 0; r < 2; ++r) {
            uint4 xv = xq[r];
            A0=dot2(wi0a[4*r+0],xv.x,A0); A1=dot2(wi0a[4*r+1],xv.y,A1);
            A2=dot2(wi0a[4*r+2],xv.z,A2); A3=dot2(wi0a[4*r+3],xv.w,A3);
            B0=dot2(wi0b[4*r+0],xv.x,B0); B1=dot2(wi0b[4*r+1],xv.y,B1);
            B2=dot2(wi0b[4*r+2],xv.z,B2); B3=dot2(wi0b[4*r+3],xv.w,B3);
        }

        float sA = qsum((A0+A1)+(A2+A3));
        float sB = qsum((B0+B1)+(B2+B3));
        float sC = qsum((C0+C1)+(C2+C3));
        float sD = qsum((D0+D1)+(D2+D3));
        float v0 = fast_tanh((hiq ? sB : sA) + bias0);   // h0(t+1)[wd]
        float v1 = fast_tanh((hiq ? sD : sC) + bias1);   // h1(t)[wd]
        if (l < 32) {
            h0h[s & 1][wd] = (_Float16)v0;
            h1h[t & 1][wd] = (_Float16)v1;
        }

        // ---- mid-chunk commit of chunk c+1 (in R), prefetch c+2.
        // Buffer (c+1)&1 holds chunk c-1, last read at s=16c-1 (barriers since).
        if (ph == 8) {
            if (c + 1 < NCHUNK) {
                uint2 pk; pk.x = packh2(R.x, R.y); pk.y = packh2(R.z, R.w);
                ((uint2*)&xs[(c + 1) & 1][0][0])[tid] = pk;
            }
            if (c + 2 < NCHUNK) R = xrow[(size_t)(c + 2) * 256 + tid];
        }
        __syncthreads();
    }

    // ================= peel: L1(T-1); h0(2047) parity 1, h1(2046) parity 0
    {
        const uint4* hp = (const uint4*)&h0h[1][q * 32];
        const uint4* gp = (const uint4*)&h1h[0][q * 32];
        float C0=0,C1=0,C2=0,C3=0, D0=0,D1=0,D2=0,D3=0;
        #pragma unroll
        for (int r = 0; r < 4; ++r) {
            uint4 hv = hp[r];
            C0=dot2(wi1a[4*r+0],hv.x,C0); C1=dot2(wi1a[4*r+1],hv.y,C1);
            C2=dot2(wi1a[4*r+2],hv.z,C2); C3=dot2(wi1a[4*r+3],hv.w,C3);
            D0=dot2(wi1b[4*r+0],hv.x,D0); D1=dot2(wi1b[4*r+1],hv.y,D1);
            D2=dot2(wi1b[4*r+2],hv.z,D2); D3=dot2(wi1b[4*r+3],hv.w,D3);
            uint4 gv = gp[r];
            C0=dot2(wh1a[4*r+0],gv.x,C0); C1=dot2(wh1a[4*r+1],gv.y,C1);
            C2=dot2(wh1a[4*r+2],gv.z,C2); C3=dot2(wh1a[4*r+3],gv.w,C3);
            D0=dot2(wh1b[4*r+0],gv.x,D0); D1=dot2(wh1b[4*r+1],gv.y,D1);
            D2=dot2(wh1b[4*r+2],gv.z,D2); D3=dot2(wh1b[4*r+3],gv.w,D3);
        }
        float sC = qsum((C0+C1)+(C2+C3));
        float sD = qsum((D0+D1)+(D2+D3));
        float v1 = fast_tanh((hiq ? sD : sC) + bias1);   // h1(2047)
        if (l < 32) h1h[1][wd] = (_Float16)v1;
    }
    __syncthreads();

    // ================= epilogue: finals are h0h[1], h1h[1]
    if (tid < OUT) {
        float acc = bfc[tid];
        const float* w = Wfc + tid * H;
        #pragma unroll 8
        for (int k = 0; k < H; ++k) acc = fmaf(w[k], (float)h1h[1][k], acc);
        out[(size_t)b * OUT + tid] = acc;
    }
    if (tid < H) {
        out[BATCH * OUT + (size_t)b * H + tid] = (float)h0h[1][tid];
    } else {
        const int u = tid - H;
        out[BATCH * OUT + BATCH * H + (size_t)b * H + u] = (float)h1h[1][u];
    }
}

} // namespace

extern "C" void kernel_launch(void* const* d_in, const int* in_sizes, int n_in,
                              void* d_out, int out_size, void* d_ws, size_t ws_size,
                              hipStream_t stream) {
    const float* x   = (const float*)d_in[0];
    const float* hid = (const float*)d_in[1];
    const float* Wi0 = (const float*)d_in[2];
    const float* bi0 = (const float*)d_in[3];
    const float* Wh0 = (const float*)d_in[4];
    const float* bh0 = (const float*)d_in[5];
    const float* Wi1 = (const float*)d_in[6];
    const float* bi1 = (const float*)d_in[7];
    const float* Wh1 = (const float*)d_in[8];
    const float* bh1 = (const float*)d_in[9];
    const float* Wfc = (const float*)d_in[10];
    const float* bfc = (const float*)d_in[11];
    float* out = (float*)d_out;

    hipLaunchKernelGGL(rnn2_scan, dim3(BATCH), dim3(BDIM), 0, stream,
                       x, hid, Wi0, bi0, Wh0, bh0, Wi1, bi1, Wh1, bh1, Wfc, bfc, out);
}

// Round 6
// 1734.680 us; speedup vs baseline: 1.0298x; 1.0298x over previous
//
#include <hip/hip_runtime.h>
#include <stdint.h>

namespace {

constexpr int T_STEPS = 2048;
constexpr int BATCH   = 512;
constexpr int IN      = 64;
constexpr int H       = 128;
constexpr int OUT     = 10;
constexpr int ROWS    = 2;     // batch rows per block
constexpr int BDIM    = 512;   // 8 waves: waves 0-3 row 0, waves 4-7 row 1
constexpr int NBLK    = BATCH / ROWS;      // 256 blocks = 1/CU
constexpr int CHUNK   = 16;    // x prefetch chunk (steps)
constexpr int NCHUNK  = T_STEPS / CHUNK;   // 128

typedef _Float16 half2v __attribute__((ext_vector_type(2)));

__device__ __forceinline__ float dot2(uint32_t a, uint32_t b, float c) {
#if __has_builtin(__builtin_amdgcn_fdot2)
    return __builtin_amdgcn_fdot2(__builtin_bit_cast(half2v, a),
                                  __builtin_bit_cast(half2v, b), c, false);
#else
    half2v av = __builtin_bit_cast(half2v, a);
    half2v bv = __builtin_bit_cast(half2v, b);
    return c + (float)av[0] * (float)bv[0] + (float)av[1] * (float)bv[1];
#endif
}

__device__ __forceinline__ uint32_t packh2(float lo, float hi) {
    half2v v; v[0] = (_Float16)lo; v[1] = (_Float16)hi;
    return __builtin_bit_cast(uint32_t, v);
}

__device__ __forceinline__ float fast_tanh(float x) {
    float e = __expf(2.0f * x);
    return 1.0f - 2.0f / (e + 1.0f);
}

// Sum over the 4-lane group {l, l^16, l^32, l^48}; result in ALL lanes.
// Inline asm with two distinct read-write operands — verified in round 5.
__device__ __forceinline__ float qsum(float v) {
    float x = v, y = v;
    asm("v_permlane16_swap_b32 %0, %1" : "+v"(x), "+v"(y));
    float s = x + y;                 // v[l] + v[l^16]
    float p = s, q = s;
    asm("v_permlane32_swap_b32 %0, %1" : "+v"(p), "+v"(q));
    return p + q;                    // full 4-group sum
}

// Fused 2-layer scan, 2 batch rows / block (wave-group per row), pipelined
// L1(t) || L0(t+1). 4-way K-split; each thread owns dims dlo, dlo+64.
__global__ __launch_bounds__(BDIM, 2) void rnn2_scan(
    const float* __restrict__ x,
    const float* __restrict__ hidden,
    const float* __restrict__ Wi0, const float* __restrict__ bi0,
    const float* __restrict__ Wh0, const float* __restrict__ bh0,
    const float* __restrict__ Wi1, const float* __restrict__ bi1,
    const float* __restrict__ Wh1, const float* __restrict__ bh1,
    const float* __restrict__ Wfc, const float* __restrict__ bfc,
    float* __restrict__ out)
{
    const int b2  = blockIdx.x * ROWS;   // first batch row of this block
    const int tid = threadIdx.x;
    const int row = tid >> 8;            // 0 or 1 (wave-uniform)
    const int u   = tid & 255;           // thread id within row-group
    const int W4  = u >> 6;              // sub-wave index within row-group
    const int l   = tid & 63;
    const int q   = l >> 4;              // K-quarter 0..3
    const int dlo = W4 * 16 + (l & 15);
    const int dhi = dlo + 64;
    const bool hiq = (q & 1) != 0;
    const int  wd  = hiq ? dhi : dlo;

    // h(t) parity: h?h[t & 1][row]; inits live in parity 1.
    __shared__ __align__(16) _Float16 h0h[2][ROWS][H];
    __shared__ __align__(16) _Float16 h1h[2][ROWS][H];
    __shared__ __align__(16) uint32_t xs[2][ROWS][CHUNK][IN / 2];  // 8 KB

    // ---- weights: f16 pairs, rows {dlo,dhi}, K-slice [q*32, q*32+32)
    uint32_t wh0a[16], wh0b[16], wi1a[16], wi1b[16], wh1a[16], wh1b[16];
    uint32_t wi0a[8], wi0b[8];
    {
        const float2* p;
        p = (const float2*)(Wh0 + dlo * H + q * 32);
        #pragma unroll
        for (int j = 0; j < 16; ++j) wh0a[j] = packh2(p[j].x, p[j].y);
        p = (const float2*)(Wh0 + dhi * H + q * 32);
        #pragma unroll
        for (int j = 0; j < 16; ++j) wh0b[j] = packh2(p[j].x, p[j].y);
        p = (const float2*)(Wi1 + dlo * H + q * 32);
        #pragma unroll
        for (int j = 0; j < 16; ++j) wi1a[j] = packh2(p[j].x, p[j].y);
        p = (const float2*)(Wi1 + dhi * H + q * 32);
        #pragma unroll
        for (int j = 0; j < 16; ++j) wi1b[j] = packh2(p[j].x, p[j].y);
        p = (const float2*)(Wh1 + dlo * H + q * 32);
        #pragma unroll
        for (int j = 0; j < 16; ++j) wh1a[j] = packh2(p[j].x, p[j].y);
        p = (const float2*)(Wh1 + dhi * H + q * 32);
        #pragma unroll
        for (int j = 0; j < 16; ++j) wh1b[j] = packh2(p[j].x, p[j].y);
        p = (const float2*)(Wi0 + dlo * IN + q * 16);
        #pragma unroll
        for (int j = 0; j < 8; ++j) wi0a[j] = packh2(p[j].x, p[j].y);
        p = (const float2*)(Wi0 + dhi * IN + q * 16);
        #pragma unroll
        for (int j = 0; j < 8; ++j) wi0b[j] = packh2(p[j].x, p[j].y);
    }
    const float bias0 = hiq ? (bi0[dhi] + bh0[dhi]) : (bi0[dlo] + bh0[dlo]);
    const float bias1 = hiq ? (bi1[dhi] + bh1[dhi]) : (bi1[dlo] + bh1[dlo]);

    // ---- init hidden into parity-1 buffers (512 threads cover 2 rows × 2 layers)
    if (tid < 256) {
        const int r = tid >> 7, d = tid & 127;
        h0h[1][r][d] = (_Float16)hidden[(b2 + r) * H + d];
    } else {
        const int v = tid - 256, r = v >> 7, d = v & 127;
        h1h[1][r][d] = (_Float16)hidden[BATCH * H + (b2 + r) * H + d];
    }

    // ---- x prefetch: chunk0 packed into LDS, chunk1 raw in regs (per row)
    const float4* xrowg = (const float4*)(x + (size_t)(b2 + row) * T_STEPS * IN);
    float4 R;
    {
        float4 v = xrowg[u];
        uint2 pk; pk.x = packh2(v.x, v.y); pk.y = packh2(v.z, v.w);
        ((uint2*)&xs[0][row][0][0])[u] = pk;
        R = xrowg[256 + u];
    }
    __syncthreads();

    // ================= peel: L0(0) -> h0(0) into h0h[0]
    {
        const uint4* hp = (const uint4*)&h0h[1][row][q * 32];
        const uint4* xq = (const uint4*)&xs[0][row][0][q * 8];
        uint4 hv0 = hp[0], hv1 = hp[1], hv2 = hp[2], hv3 = hp[3];
        uint4 xv0 = xq[0], xv1 = xq[1];
        float A0=0,A1=0,A2=0,A3=0, B0=0,B1=0,B2=0,B3=0;
        const uint4 hvs[4] = {hv0, hv1, hv2, hv3};
        const uint4 xvs[2] = {xv0, xv1};
        #pragma unroll
        for (int r = 0; r < 4; ++r) {
            uint4 hv = hvs[r];
            A0=dot2(wh0a[4*r+0],hv.x,A0); A1=dot2(wh0a[4*r+1],hv.y,A1);
            A2=dot2(wh0a[4*r+2],hv.z,A2); A3=dot2(wh0a[4*r+3],hv.w,A3);
            B0=dot2(wh0b[4*r+0],hv.x,B0); B1=dot2(wh0b[4*r+1],hv.y,B1);
            B2=dot2(wh0b[4*r+2],hv.z,B2); B3=dot2(wh0b[4*r+3],hv.w,B3);
        }
        #pragma unroll
        for (int r = 0; r < 2; ++r) {
            uint4 xv = xvs[r];
            A0=dot2(wi0a[4*r+0],xv.x,A0); A1=dot2(wi0a[4*r+1],xv.y,A1);
            A2=dot2(wi0a[4*r+2],xv.z,A2); A3=dot2(wi0a[4*r+3],xv.w,A3);
            B0=dot2(wi0b[4*r+0],xv.x,B0); B1=dot2(wi0b[4*r+1],xv.y,B1);
            B2=dot2(wi0b[4*r+2],xv.z,B2); B3=dot2(wi0b[4*r+3],xv.w,B3);
        }
        float sA = qsum((A0+A1)+(A2+A3));
        float sB = qsum((B0+B1)+(B2+B3));
        float v0 = fast_tanh((hiq ? sB : sA) + bias0);
        if (l < 32) h0h[0][row][wd] = (_Float16)v0;
    }
    __syncthreads();

    // ================= main loop: interval t computes L1(t) || L0(t+1)
    for (int t = 0; t < T_STEPS - 1; ++t) {
        const int s  = t + 1;
        const int c  = s >> 4;
        const int ph = s & (CHUNK - 1);
        const int rp = t & 1;

        const uint4* hp = (const uint4*)&h0h[rp][row][q * 32];      // h0(t)
        const uint4* gp = (const uint4*)&h1h[rp ^ 1][row][q * 32];  // h1(t-1)
        const uint4* xq = (const uint4*)&xs[c & 1][row][ph][q * 8];

        // hoist all LDS reads so they issue as one cluster
        uint4 hv0 = hp[0], hv1 = hp[1], hv2 = hp[2], hv3 = hp[3];
        uint4 gv0 = gp[0], gv1 = gp[1], gv2 = gp[2], gv3 = gp[3];
        uint4 xv0 = xq[0], xv1 = xq[1];
        const uint4 hvs[4] = {hv0, hv1, hv2, hv3};
        const uint4 gvs[4] = {gv0, gv1, gv2, gv3};
        const uint4 xvs[2] = {xv0, xv1};

        __builtin_amdgcn_s_setprio(1);
        float A0=0,A1=0,A2=0,A3=0;   // L0(t+1), dlo
        float B0=0,B1=0,B2=0,B3=0;   // L0(t+1), dhi
        float C0=0,C1=0,C2=0,C3=0;   // L1(t),   dlo
        float D0=0,D1=0,D2=0,D3=0;   // L1(t),   dhi
        #pragma unroll
        for (int r = 0; r < 4; ++r) {
            uint4 hv = hvs[r];
            A0=dot2(wh0a[4*r+0],hv.x,A0); A1=dot2(wh0a[4*r+1],hv.y,A1);
            A2=dot2(wh0a[4*r+2],hv.z,A2); A3=dot2(wh0a[4*r+3],hv.w,A3);
            B0=dot2(wh0b[4*r+0],hv.x,B0); B1=dot2(wh0b[4*r+1],hv.y,B1);
            B2=dot2(wh0b[4*r+2],hv.z,B2); B3=dot2(wh0b[4*r+3],hv.w,B3);
            C0=dot2(wi1a[4*r+0],hv.x,C0); C1=dot2(wi1a[4*r+1],hv.y,C1);
            C2=dot2(wi1a[4*r+2],hv.z,C2); C3=dot2(wi1a[4*r+3],hv.w,C3);
            D0=dot2(wi1b[4*r+0],hv.x,D0); D1=dot2(wi1b[4*r+1],hv.y,D1);
            D2=dot2(wi1b[4*r+2],hv.z,D2); D3=dot2(wi1b[4*r+3],hv.w,D3);
            uint4 gv = gvs[r];
            C0=dot2(wh1a[4*r+0],gv.x,C0); C1=dot2(wh1a[4*r+1],gv.y,C1);
            C2=dot2(wh1a[4*r+2],gv.z,C2); C3=dot2(wh1a[4*r+3],gv.w,C3);
            D0=dot2(wh1b[4*r+0],gv.x,D0); D1=dot2(wh1b[4*r+1],gv.y,D1);
            D2=dot2(wh1b[4*r+2],gv.z,D2); D3=dot2(wh1b[4*r+3],gv.w,D3);
        }
        #pragma unroll
        for (int r = 0; r < 2; ++r) {
            uint4 xv = xvs[r];
            A0=dot2(wi0a[4*r+0],xv.x,A0); A1=dot2(wi0a[4*r+1],xv.y,A1);
            A2=dot2(wi0a[4*r+2],xv.z,A2); A3=dot2(wi0a[4*r+3],xv.w,A3);
            B0=dot2(wi0b[4*r+0],xv.x,B0); B1=dot2(wi0b[4*r+1],xv.y,B1);
            B2=dot2(wi0b[4*r+2],xv.z,B2); B3=dot2(wi0b[4*r+3],xv.w,B3);
        }

        float sA = qsum((A0+A1)+(A2+A3));
        float sB = qsum((B0+B1)+(B2+B3));
        float sC = qsum((C0+C1)+(C2+C3));
        float sD = qsum((D0+D1)+(D2+D3));
        float v0 = fast_tanh((hiq ? sB : sA) + bias0);   // h0(t+1)[wd]
        float v1 = fast_tanh((hiq ? sD : sC) + bias1);   // h1(t)[wd]
        __builtin_amdgcn_s_setprio(0);

        // one unpredicated ds_write_b16: lanes<32 -> h0(t+1), lanes>=32 -> h1(t)
        {
            const float val = (l < 32) ? v0 : v1;
            _Float16* wa = (l < 32) ? &h0h[s & 1][row][wd] : &h1h[t & 1][row][wd];
            *wa = (_Float16)val;
        }

        // ---- mid-chunk commit of chunk c+1 (in R), prefetch c+2 (per row)
        if (ph == 8) {
            if (c + 1 < NCHUNK) {
                uint2 pk; pk.x = packh2(R.x, R.y); pk.y = packh2(R.z, R.w);
                ((uint2*)&xs[(c + 1) & 1][row][0][0])[u] = pk;
            }
            if (c + 2 < NCHUNK) R = xrowg[(size_t)(c + 2) * 256 + u];
        }
        __syncthreads();
    }

    // ================= peel: L1(T-1); h0(2047) parity 1, h1(2046) parity 0
    {
        const uint4* hp = (const uint4*)&h0h[1][row][q * 32];
        const uint4* gp = (const uint4*)&h1h[0][row][q * 32];
        float C0=0,C1=0,C2=0,C3=0, D0=0,D1=0,D2=0,D3=0;
        #pragma unroll
        for (int r = 0; r < 4; ++r) {
            uint4 hv = hp[r];
            C0=dot2(wi1a[4*r+0],hv.x,C0); C1=dot2(wi1a[4*r+1],hv.y,C1);
            C2=dot2(wi1a[4*r+2],hv.z,C2); C3=dot2(wi1a[4*r+3],hv.w,C3);
            D0=dot2(wi1b[4*r+0],hv.x,D0); D1=dot2(wi1b[4*r+1],hv.y,D1);
            D2=dot2(wi1b[4*r+2],hv.z,D2); D3=dot2(wi1b[4*r+3],hv.w,D3);
            uint4 gv = gp[r];
            C0=dot2(wh1a[4*r+0],gv.x,C0); C1=dot2(wh1a[4*r+1],gv.y,C1);
            C2=dot2(wh1a[4*r+2],gv.z,C2); C3=dot2(wh1a[4*r+3],gv.w,C3);
            D0=dot2(wh1b[4*r+0],gv.x,D0); D1=dot2(wh1b[4*r+1],gv.y,D1);
            D2=dot2(wh1b[4*r+2],gv.z,D2); D3=dot2(wh1b[4*r+3],gv.w,D3);
        }
        float sC = qsum((C0+C1)+(C2+C3));
        float sD = qsum((D0+D1)+(D2+D3));
        float v1 = fast_tanh((hiq ? sD : sC) + bias1);   // h1(2047)
        if (l < 32) h1h[1][row][wd] = (_Float16)v1;
    }
    __syncthreads();

    // ================= epilogue: finals are h0h[1][row], h1h[1][row]
    if ((u & 127) < OUT && u < 128 + OUT) {
        // threads u in [0,OUT) handle row's? -- use explicit mapping below
    }
    {
        const int o = u & 127;
        const int r = row;   // row from wave-group
        if (u < OUT) {
            float acc = bfc[o];
            const float* w = Wfc + o * H;
            #pragma unroll 8
            for (int k = 0; k < H; ++k) acc = fmaf(w[k], (float)h1h[1][r][k], acc);
            out[(size_t)(b2 + r) * OUT + o] = acc;
        }
        if (u < 128) {
            out[BATCH * OUT + (size_t)(b2 + r) * H + u] = (float)h0h[1][r][u];
        } else {
            const int d = u - 128;
            out[BATCH * OUT + BATCH * H + (size_t)(b2 + r) * H + d] = (float)h1h[1][r][d];
        }
    }
}

} // namespace

extern "C" void kernel_launch(void* const* d_in, const int* in_sizes, int n_in,
                              void* d_out, int out_size, void* d_ws, size_t ws_size,
                              hipStream_t stream) {
    const float* x   = (const float*)d_in[0];
    const float* hid = (const float*)d_in[1];
    const float* Wi0 = (const float*)d_in[2];
    const float* bi0 = (const float*)d_in[3];
    const float* Wh0 = (const float*)d_in[4];
    const float* bh0 = (const float*)d_in[5];
    const float* Wi1 = (const float*)d_in[6];
    const float* bi1 = (const float*)d_in[7];
    const float* Wh1 = (const float*)d_in[8];
    const float* bh1 = (const float*)d_in[9];
    const float* Wfc = (const float*)d_in[10];
    const float* bfc = (const float*)d_in[11];
    float* out = (float*)d_out;

    hipLaunchKernelGGL(rnn2_scan, dim3(NBLK), dim3(BDIM), 0, stream,
                       x, hid, Wi0, bi0, Wh0, bh0, Wi1, bi1, Wh1, bh1, Wfc, bfc, out);
}